// Round 15
// baseline (99.843 us; speedup 1.0000x reference)
//
#include <hip/hip_runtime.h>
#include <math.h>

#define NS 4
#define HDIM 1024
#define DDIM 4096           // NS*HDIM
#define TOK_B 32            // tokens per block (dots)
#define KCH 512             // K-chunk per block (8 chunks over K=4096)
#define NPS 16              // partial sets = 8 kc * 2 kh
#define HC_EPS_F 1e-6f
#define NORM_EPS_F 1e-6f

typedef __attribute__((ext_vector_type(8))) short short8;
typedef __attribute__((ext_vector_type(4))) float f32x4;

__device__ __forceinline__ float frcp(float v) { return __builtin_amdgcn_rcpf(v); }

__device__ __forceinline__ void gload_lds16(const float* g, float* l) {
  __builtin_amdgcn_global_load_lds(
      (const __attribute__((address_space(1))) void*)g,
      (__attribute__((address_space(3))) void*)l, 16, 0, 0);
}

// fp32 -> bf16 hi (truncate) + lo (residual). 3-term MFMA ~ fp32 accuracy.
#define CVT_PAIR(j, f0, f1)                                                     \
  { unsigned p0 = __float_as_uint(f0), p1 = __float_as_uint(f1);                \
    H.u[j] = (p1 & 0xFFFF0000u) | (p0 >> 16);                                   \
    unsigned q0 = __float_as_uint((f0) - __uint_as_float(p0 & 0xFFFF0000u));    \
    unsigned q1 = __float_as_uint((f1) - __uint_as_float(p1 & 0xFFFF0000u));    \
    L.u[j] = (q1 & 0xFFFF0000u) | (q0 >> 16); }

__device__ __forceinline__ void cvt_hl(const float4 a, const float4 b,
                                       short8& hi, short8& lo) {
  union { unsigned u[4]; short8 s; } H, L;
  CVT_PAIR(0, a.x, a.y)
  CVT_PAIR(1, a.z, a.w)
  CVT_PAIR(2, b.x, b.y)
  CVT_PAIR(3, b.z, b.w)
  hi = H.s; lo = L.s;
}

// ============ K1: LDS-staged MFMA partial GEMM. ============
// Block: 32 tokens x 512 K. Stage x via global_load_lds (in-flight bytes live in
// the LDS-DMA queue, NOT VGPRs — the R7-R14 register-staging plateau's fix).
// Wave roles: th=wave&1 (token half), kh=wave>>1 (K half, 256). 8 MFMA steps each.
// Partials wp[ps][tok][25], ps = kc*2+kh (16 sets), stored in OUT scratch.
__launch_bounds__(256, 2)   // VGPR cap 128 (toolchain law R7-R11); demand ~90-100
__global__ void mhc_dots_mfma(const float* __restrict__ x,
                              const float* __restrict__ hc_fn,
                              float* __restrict__ wp, int ntok) {
  __shared__ float xs[TOK_B * KCH];    // 64 KB -> 2 blocks/CU
  const int tid  = threadIdx.x;
  const int lane = tid & 63;
  const int wave = tid >> 6;
  const int mt = blockIdx.x >> 3;      // token-tile index
  const int kc = blockIdx.x & 7;       // K-chunk index
  const long long tok0 = (long long)mt * TOK_B;
  const int k0 = kc * KCH;

  // ---- stage 64 KB: 16 chunks/thread, all in flight before one barrier ----
  // float4 slot S+lane holds x[tok0 + (S+lane)>>7][k0 + ((S+lane)&127)*4 ..+3]
  #pragma unroll
  for (int c = 0; c < 16; ++c) {
    const int S = c * 256 + wave * 64;           // wave-uniform float4 base
    const int t = S >> 7;                        // uniform within wave (64|S)
    const int b = (S & 127) + lane;              // per-lane float4-in-row
    gload_lds16(x + (tok0 + t) * DDIM + k0 + b * 4, xs + (size_t)S * 4);
  }

  // B pointers (fn, L2-resident) — computed while stages fly
  const int th = wave & 1;             // token half
  const int kh = wave >> 1;            // K half
  const int row = lane & 15;           // A row (token) / B col (m) / C col
  const int ks  = lane >> 4;           // k-slice

  const float4* bp0 = (const float4*)(hc_fn + (long long)row * DDIM + k0 + kh * 256) + ks * 2;
  const int fr1c = (row < 8) ? (16 + row) : 23;
  const float4* bp1 = (const float4*)(hc_fn + (long long)fr1c * DDIM + k0 + kh * 256) + ks * 2;
  const bool v1 = (row < 8);
  const float4 z4 = {0.f, 0.f, 0.f, 0.f};

  f32x4 acc0 = {0.f, 0.f, 0.f, 0.f};
  f32x4 acc1 = {0.f, 0.f, 0.f, 0.f};
  float ssq = 0.f;

  // B 1-deep prefetch (registers; only 4 float4 of payload)
  float4 b00_c = bp0[0], b01_c = bp0[1];
  float4 b10_c = v1 ? bp1[0] : z4, b11_c = v1 ? bp1[1] : z4;

  __syncthreads();                     // drains staging vmcnt

  const float* a_base = xs + (size_t)(th * 16 + row) * KCH + kh * 256 + ks * 8;

  #pragma unroll
  for (int s = 0; s < 8; ++s) {        // 8 K-steps of 32
    float4 b00_n, b01_n, b10_n, b11_n;
    if (s < 7) {
      const int o = (s + 1) * 8;
      b00_n = bp0[o]; b01_n = bp0[o + 1];
      b10_n = v1 ? bp1[o] : z4; b11_n = v1 ? bp1[o + 1] : z4;
    }
    const float4 a0 = *(const float4*)(a_base + s * 32);
    const float4 a1 = *(const float4*)(a_base + s * 32 + 4);

    ssq = fmaf(a0.x, a0.x, fmaf(a0.y, a0.y, fmaf(a0.z, a0.z, fmaf(a0.w, a0.w, ssq))));
    ssq = fmaf(a1.x, a1.x, fmaf(a1.y, a1.y, fmaf(a1.z, a1.z, fmaf(a1.w, a1.w, ssq))));

    short8 ahi, alo, b0hi, b0lo, b1hi, b1lo;
    cvt_hl(a0, a1, ahi, alo);
    cvt_hl(b00_c, b01_c, b0hi, b0lo);
    cvt_hl(b10_c, b11_c, b1hi, b1lo);

    acc0 = __builtin_amdgcn_mfma_f32_16x16x32_bf16(ahi, b0hi, acc0, 0, 0, 0);
    acc1 = __builtin_amdgcn_mfma_f32_16x16x32_bf16(ahi, b1hi, acc1, 0, 0, 0);
    acc0 = __builtin_amdgcn_mfma_f32_16x16x32_bf16(ahi, b0lo, acc0, 0, 0, 0);
    acc1 = __builtin_amdgcn_mfma_f32_16x16x32_bf16(ahi, b1lo, acc1, 0, 0, 0);
    acc0 = __builtin_amdgcn_mfma_f32_16x16x32_bf16(alo, b0hi, acc0, 0, 0, 0);
    acc1 = __builtin_amdgcn_mfma_f32_16x16x32_bf16(alo, b1hi, acc1, 0, 0, 0);

    if (s < 7) {
      b00_c = b00_n; b01_c = b01_n;
      b10_c = b10_n; b11_c = b11_n;
    }
  }

  // ssq: combine the 4 k-slices of each row (lanes l, l^16, l^32 share row)
  ssq += __shfl_xor(ssq, 16, 64);
  ssq += __shfl_xor(ssq, 32, 64);

  // direct partial stores: wp[ps][tok][25], ps = kc*2 + kh
  const int ps = kc * 2 + kh;
  float* wpk = wp + (long long)ps * ntok * 25;
  const long long tbase = tok0 + th * 16;
  if (lane < 16) wpk[(tbase + lane) * 25 + 24] = ssq;
  const int rq = lane >> 4;
  #pragma unroll
  for (int r = 0; r < 4; ++r)
    wpk[(tbase + rq * 4 + r) * 25 + row] = acc0[r];
  if (row < 8) {
    #pragma unroll
    for (int r = 0; r < 4; ++r)
      wpk[(tbase + rq * 4 + r) * 25 + 16 + row] = acc1[r];
  }
}

// ============ K1b: reduce 16 partial sets + sinkhorn -> gates[tok][24]. ============
__launch_bounds__(256, 4)
__global__ void mhc_sinkhorn(const float* __restrict__ wp,
                             const float* __restrict__ hc_scale,
                             const float* __restrict__ hc_base,
                             float* __restrict__ gates, int ntok) {
  const int lane = threadIdx.x & 63;
  const int wave = threadIdx.x >> 6;
  const long long tok = (long long)blockIdx.x * 16 + wave * 4 + (lane >> 4);
  const int e = lane & 15;             // i*4 + j

  const long long kstride = (long long)ntok * 25;
  const float* b = wp + tok * 25;
  float sres = 0.f, ssq = 0.f, spre = 0.f, spost = 0.f;
  #pragma unroll
  for (int ps = 0; ps < NPS; ++ps) {
    const float* p = b + ps * kstride;
    sres += p[8 + e];
    ssq  += p[24];
    if (e < NS) { spre += p[e]; spost += p[NS + e]; }
  }

  const float rs = rsqrtf(ssq * (1.0f / DDIM) + NORM_EPS_F);
  const float s0 = hc_scale[0], s1 = hc_scale[1], s2 = hc_scale[2];

  float h = sres * rs * s2 + hc_base[8 + e];
  float mx = fmaxf(h, __shfl_xor(h, 1, 4));
  mx = fmaxf(mx, __shfl_xor(mx, 2, 4));
  float ex = expf(h - mx);
  float sm = ex + __shfl_xor(ex, 1, 4);
  sm += __shfl_xor(sm, 2, 4);
  h = ex * frcp(sm) + HC_EPS_F;
  float cs = h + __shfl_xor(h, 4, 16);
  cs += __shfl_xor(cs, 8, 16);
  h *= frcp(cs + HC_EPS_F);
  #pragma unroll 1
  for (int itn = 0; itn < 19; ++itn) {
    float rsum = h + __shfl_xor(h, 1, 4);
    rsum += __shfl_xor(rsum, 2, 4);
    h *= frcp(rsum + HC_EPS_F);
    float csum = h + __shfl_xor(h, 4, 16);
    csum += __shfl_xor(csum, 8, 16);
    h *= frcp(csum + HC_EPS_F);
  }
  float* g = gates + tok * 24;
  g[8 + e] = h;
  if (e < NS) {
    g[e] = frcp(1.0f + expf(-(spre * rs * s0 + hc_base[e]))) + HC_EPS_F;
    g[NS + e] = 2.0f * frcp(1.0f + expf(-(spost * rs * s1 + hc_base[NS + e])));
  }
}

// ============ K2: gates + x -> out (pure stream, at write roofline ~21us) ============
__launch_bounds__(256, 8)
__global__ void mhc_out(const float* __restrict__ x,
                        const float* __restrict__ gates,
                        float* __restrict__ out) {
  const long long token = blockIdx.x;
  const int q = threadIdx.x;           // float4 index in [0,256)

  const float* g = gates + token * 24; // uniform address -> scalar loads
  float hp[NS], hq[NS], hr[NS][NS];
  #pragma unroll
  for (int i = 0; i < NS; ++i) {
    hp[i] = g[i];
    hq[i] = g[NS + i];
    #pragma unroll
    for (int j = 0; j < NS; ++j) hr[i][j] = g[8 + i * NS + j];
  }

  const float4* xb = (const float4*)(x + token * DDIM);
  float4 xv[NS];
  #pragma unroll
  for (int i = 0; i < NS; ++i) xv[i] = xb[i * 256 + q];

  float4 y;
  y.x = hp[0]*xv[0].x + hp[1]*xv[1].x + hp[2]*xv[2].x + hp[3]*xv[3].x;
  y.y = hp[0]*xv[0].y + hp[1]*xv[1].y + hp[2]*xv[2].y + hp[3]*xv[3].y;
  y.z = hp[0]*xv[0].z + hp[1]*xv[1].z + hp[2]*xv[2].z + hp[3]*xv[3].z;
  y.w = hp[0]*xv[0].w + hp[1]*xv[1].w + hp[2]*xv[2].w + hp[3]*xv[3].w;

  float4* ob = (float4*)(out + token * DDIM);
  #pragma unroll
  for (int n = 0; n < NS; ++n) {
    float4 o;
    o.x = hq[n]*y.x + hr[0][n]*xv[0].x + hr[1][n]*xv[1].x + hr[2][n]*xv[2].x + hr[3][n]*xv[3].x;
    o.y = hq[n]*y.y + hr[0][n]*xv[0].y + hr[1][n]*xv[1].y + hr[2][n]*xv[2].y + hr[3][n]*xv[3].y;
    o.z = hq[n]*y.z + hr[0][n]*xv[0].z + hr[1][n]*xv[1].z + hr[2][n]*xv[2].z + hr[3][n]*xv[3].z;
    o.w = hq[n]*y.w + hr[0][n]*xv[0].w + hr[1][n]*xv[1].w + hr[2][n]*xv[2].w + hr[3][n]*xv[3].w;
    ob[n * 256 + q] = o;
  }
}

extern "C" void kernel_launch(void* const* d_in, const int* in_sizes, int n_in,
                              void* d_out, int out_size, void* d_ws, size_t ws_size,
                              hipStream_t stream) {
  const float* x        = (const float*)d_in[0];
  const float* hc_fn    = (const float*)d_in[1];
  const float* hc_scale = (const float*)d_in[2];
  const float* hc_base  = (const float*)d_in[3];
  float* out = (float*)d_out;

  const int ntok = in_sizes[0] / DDIM;       // B*S = 8192
  float* gates = (float*)d_ws;               // ntok*24*4 = 786 KB (PROVEN within ws_size)
  float* wp    = out;                        // partials wp[16][ntok][25] = 13.1 MB scratch;
                                             // K2 fully overwrites out afterwards.

  mhc_dots_mfma<<<(ntok / TOK_B) * 8, 256, 0, stream>>>(x, hc_fn, wp, ntok);
  mhc_sinkhorn<<<ntok / 16, 256, 0, stream>>>(wp, hc_scale, hc_base, gates, ntok);
  mhc_out<<<ntok, 256, 0, stream>>>(x, gates, out);
}